// Round 1
// baseline (12.096 us; speedup 1.0000x reference)
//
#include <hip/hip_runtime.h>

// Problem constants (fixed by the reference)
#define LNUM   12
#define PDIM   4
#define IN_F   1024
#define OUT_F  1024
#define IN_P   256      // IN_F / PDIM
#define OUT_P  256      // OUT_F / PDIM
#define NBLK   96       // 2*L*P
#define M2L    24       // 2*L
#define OUT_COLS 24576  // 2*L*OUT_F
#define BATCH  128

// One block per (s, m): s in [0,128), m in [0,24).
// Phase 1: 4 waves each compute v[w][j] for n = 4m+w.
// Phase 2: 256 threads write one 1024-float output row (float4 each).
__global__ __launch_bounds__(256) void phm_fused_kernel(
    const float* __restrict__ x,     // (128, 1024)
    const float* __restrict__ Wl,    // (96*256, 1) -> Wl[n*256 + k]
    const float* __restrict__ Wr,    // (96, 256)   -> Wr[n*256 + l]
    const float* __restrict__ rule,  // (32, 4)     -> rule[(q*4+i)*4 + j], q = n%8
    const float* __restrict__ b,     // (24576,)
    float* __restrict__ out)         // (128, 24576)
{
    __shared__ float4 xs[IN_F / 4];  // one x row, 4 KB
    __shared__ float  vsm[4][4];     // [p][j]

    const int bid  = blockIdx.x;
    const int s    = bid / M2L;
    const int m    = bid - s * M2L;
    const int tid  = threadIdx.x;
    const int w    = tid >> 6;   // wave id 0..3
    const int lane = tid & 63;

    // Stage x[s, :] into LDS (coalesced float4)
    xs[tid] = reinterpret_cast<const float4*>(x + (size_t)s * IN_F)[tid];
    __syncthreads();

    // ---- Phase 1: wave w handles n = 4m + w ----
    {
        const int n = 4 * m + w;
        const float4 wv = reinterpret_cast<const float4*>(Wl + n * IN_P)[lane];

        float4 a0 = xs[0 * 64 + lane];
        float4 a1 = xs[1 * 64 + lane];
        float4 a2 = xs[2 * 64 + lane];
        float4 a3 = xs[3 * 64 + lane];
        float u0 = a0.x * wv.x + a0.y * wv.y + a0.z * wv.z + a0.w * wv.w;
        float u1 = a1.x * wv.x + a1.y * wv.y + a1.z * wv.z + a1.w * wv.w;
        float u2 = a2.x * wv.x + a2.y * wv.y + a2.z * wv.z + a2.w * wv.w;
        float u3 = a3.x * wv.x + a3.y * wv.y + a3.z * wv.z + a3.w * wv.w;

        // 64-lane butterfly reduction on all four partials
        #pragma unroll
        for (int mask = 1; mask < 64; mask <<= 1) {
            u0 += __shfl_xor(u0, mask, 64);
            u1 += __shfl_xor(u1, mask, 64);
            u2 += __shfl_xor(u2, mask, 64);
            u3 += __shfl_xor(u3, mask, 64);
        }

        if (lane < 4) {
            const int j = lane;
            const int q = n & 7;  // rule tile index
            const float v = rule[(q * 4 + 0) * 4 + j] * u0
                          + rule[(q * 4 + 1) * 4 + j] * u1
                          + rule[(q * 4 + 2) * 4 + j] * u2
                          + rule[(q * 4 + 3) * 4 + j] * u3;
            vsm[w][j] = v;
        }
    }
    __syncthreads();

    // ---- Phase 2: write one output row chunk of 1024 floats ----
    {
        const int j = tid >> 6;            // 0..3
        const int l = (tid & 63) * 4;      // 0..252 step 4
        const int c = m * OUT_F + j * OUT_P + l;

        float4 acc = reinterpret_cast<const float4*>(b + c)[0];
        #pragma unroll
        for (int p = 0; p < 4; ++p) {
            const float vv = vsm[p][j];
            const float4 wr = reinterpret_cast<const float4*>(Wr + (4 * m + p) * OUT_P + l)[0];
            acc.x += vv * wr.x;
            acc.y += vv * wr.y;
            acc.z += vv * wr.z;
            acc.w += vv * wr.w;
        }
        reinterpret_cast<float4*>(out + (size_t)s * OUT_COLS + c)[0] = acc;
    }
}

extern "C" void kernel_launch(void* const* d_in, const int* in_sizes, int n_in,
                              void* d_out, int out_size, void* d_ws, size_t ws_size,
                              hipStream_t stream) {
    const float* x    = (const float*)d_in[0];  // (128, 1024)
    const float* Wl   = (const float*)d_in[1];  // (24576, 1)
    const float* Wr   = (const float*)d_in[2];  // (96, 256)
    const float* rule = (const float*)d_in[3];  // (32, 4)
    const float* b    = (const float*)d_in[4];  // (24576,)
    float* out = (float*)d_out;                 // (128, 24576)

    dim3 grid(BATCH * M2L);   // 3072 blocks: one per (s, m)
    dim3 block(256);
    phm_fused_kernel<<<grid, block, 0, stream>>>(x, Wl, Wr, rule, b, out);
}

// Round 2
// 11.940 us; speedup vs baseline: 1.0131x; 1.0131x over previous
//
#include <hip/hip_runtime.h>

// Problem constants (fixed by the reference)
#define LNUM   12
#define PDIM   4
#define IN_F   1024
#define OUT_F  1024
#define IN_P   256      // IN_F / PDIM
#define OUT_P  256      // OUT_F / PDIM
#define NBLK   96       // 2*L*P
#define M2L    24       // 2*L
#define OUT_COLS 24576  // 2*L*OUT_F
#define BATCH  128

// One WAVE per (s, m) task — no LDS, no barriers, fully independent waves.
// Each wave:
//   phase 1: for p=0..3 (n=4m+p): u_i = <x[s, i*256:...], Wl[n,:]> via per-lane
//            float4 MAC + 6-round shfl_xor butterfly (all lanes end with sums),
//            then apply the 4x4 rule per-lane into v[p][j] (registers only).
//   phase 2: y[s, m*1024 + j*256 + l] = b[...] + sum_p v[p][j] * Wr[4m+p, l]
//            (4 coalesced 1KB wave-stores).
__global__ __launch_bounds__(256) void phm_fused_kernel(
    const float* __restrict__ x,     // (128, 1024)
    const float* __restrict__ Wl,    // (96*256,)  Wl[n*256 + k]
    const float* __restrict__ Wr,    // (96, 256)  Wr[n*256 + l]
    const float* __restrict__ rule,  // (32, 4)    rule[(q*4+i)*4 + j], q = n%8
    const float* __restrict__ b,     // (24576,)
    float* __restrict__ out)         // (128, 24576)
{
    const int tid  = threadIdx.x;
    const int w    = tid >> 6;
    const int lane = tid & 63;
    const int task = blockIdx.x * 4 + w;   // 0 .. 3071
    const int s    = task / M2L;
    const int m    = task - s * M2L;

    // ---- load x row into registers (16 floats/lane) ----
    const float4* xrow = reinterpret_cast<const float4*>(x + (size_t)s * IN_F);
    const float4 xa0 = xrow[0 * 64 + lane];
    const float4 xa1 = xrow[1 * 64 + lane];
    const float4 xa2 = xrow[2 * 64 + lane];
    const float4 xa3 = xrow[3 * 64 + lane];

    // ---- independent loads for phase 2 (no dependence on phase 1; can hoist) ----
    float4 wr[4];
    #pragma unroll
    for (int p = 0; p < 4; ++p)
        wr[p] = reinterpret_cast<const float4*>(Wr + (4 * m + p) * OUT_P)[lane];
    float4 bv[4];
    #pragma unroll
    for (int j = 0; j < 4; ++j)
        bv[j] = reinterpret_cast<const float4*>(b + m * OUT_F + j * OUT_P)[lane];

    // ---- phase 1: v[p][j], all in registers ----
    float v[4][4];
    #pragma unroll
    for (int p = 0; p < 4; ++p) {
        const int n = 4 * m + p;
        const float4 wl = reinterpret_cast<const float4*>(Wl + n * IN_P)[lane];

        float u0 = xa0.x * wl.x + xa0.y * wl.y + xa0.z * wl.z + xa0.w * wl.w;
        float u1 = xa1.x * wl.x + xa1.y * wl.y + xa1.z * wl.z + xa1.w * wl.w;
        float u2 = xa2.x * wl.x + xa2.y * wl.y + xa2.z * wl.z + xa2.w * wl.w;
        float u3 = xa3.x * wl.x + xa3.y * wl.y + xa3.z * wl.z + xa3.w * wl.w;

        #pragma unroll
        for (int mask = 1; mask < 64; mask <<= 1) {
            u0 += __shfl_xor(u0, mask, 64);
            u1 += __shfl_xor(u1, mask, 64);
            u2 += __shfl_xor(u2, mask, 64);
            u3 += __shfl_xor(u3, mask, 64);
        }

        const int q = n & 7;
        const float* rq = rule + q * 16;
        #pragma unroll
        for (int j = 0; j < 4; ++j)
            v[p][j] = rq[0 * 4 + j] * u0 + rq[1 * 4 + j] * u1
                    + rq[2 * 4 + j] * u2 + rq[3 * 4 + j] * u3;
    }

    // ---- phase 2: write 1024 floats (4 x 1KB coalesced wave-stores) ----
    float* orow = out + (size_t)s * OUT_COLS + m * OUT_F;
    #pragma unroll
    for (int j = 0; j < 4; ++j) {
        float4 acc = bv[j];
        #pragma unroll
        for (int p = 0; p < 4; ++p) {
            acc.x += v[p][j] * wr[p].x;
            acc.y += v[p][j] * wr[p].y;
            acc.z += v[p][j] * wr[p].z;
            acc.w += v[p][j] * wr[p].w;
        }
        reinterpret_cast<float4*>(orow + j * OUT_P)[lane] = acc;
    }
}

extern "C" void kernel_launch(void* const* d_in, const int* in_sizes, int n_in,
                              void* d_out, int out_size, void* d_ws, size_t ws_size,
                              hipStream_t stream) {
    const float* x    = (const float*)d_in[0];
    const float* Wl   = (const float*)d_in[1];
    const float* Wr   = (const float*)d_in[2];
    const float* rule = (const float*)d_in[3];
    const float* b    = (const float*)d_in[4];
    float* out = (float*)d_out;

    dim3 grid((BATCH * M2L) / 4);  // 768 blocks, 4 independent waves each
    dim3 block(256);
    phm_fused_kernel<<<grid, block, 0, stream>>>(x, Wl, Wr, rule, b, out);
}

// Round 3
// 11.343 us; speedup vs baseline: 1.0664x; 1.0526x over previous
//
#include <hip/hip_runtime.h>

// Problem constants (fixed by the reference)
#define LNUM   12
#define PDIM   4
#define IN_F   1024
#define OUT_F  1024
#define IN_P   256      // IN_F / PDIM
#define OUT_P  256      // OUT_F / PDIM
#define NBLK   96       // 2*L*P
#define M2L    24       // 2*L
#define OUT_COLS 24576  // 2*L*OUT_F
#define BATCH  128

// One single-wave BLOCK per (s, m) task — 3072 blocks x 64 threads.
// Identical math to R2; only the dispatch granularity changes (probe for
// launch-overhead floor vs kernel-structure sensitivity).
__global__ __launch_bounds__(64) void phm_fused_kernel(
    const float* __restrict__ x,     // (128, 1024)
    const float* __restrict__ Wl,    // (96*256,)  Wl[n*256 + k]
    const float* __restrict__ Wr,    // (96, 256)  Wr[n*256 + l]
    const float* __restrict__ rule,  // (32, 4)    rule[(q*4+i)*4 + j], q = n%8
    const float* __restrict__ b,     // (24576,)
    float* __restrict__ out)         // (128, 24576)
{
    const int lane = threadIdx.x;          // 0..63
    const int task = blockIdx.x;           // 0 .. 3071
    const int s    = task / M2L;
    const int m    = task - s * M2L;

    // ---- load x row into registers (16 floats/lane) ----
    const float4* xrow = reinterpret_cast<const float4*>(x + (size_t)s * IN_F);
    const float4 xa0 = xrow[0 * 64 + lane];
    const float4 xa1 = xrow[1 * 64 + lane];
    const float4 xa2 = xrow[2 * 64 + lane];
    const float4 xa3 = xrow[3 * 64 + lane];

    // ---- independent loads for phase 2 (no dependence on phase 1) ----
    float4 wr[4];
    #pragma unroll
    for (int p = 0; p < 4; ++p)
        wr[p] = reinterpret_cast<const float4*>(Wr + (4 * m + p) * OUT_P)[lane];
    float4 bv[4];
    #pragma unroll
    for (int j = 0; j < 4; ++j)
        bv[j] = reinterpret_cast<const float4*>(b + m * OUT_F + j * OUT_P)[lane];

    // ---- phase 1: v[p][j], all in registers ----
    float v[4][4];
    #pragma unroll
    for (int p = 0; p < 4; ++p) {
        const int n = 4 * m + p;
        const float4 wl = reinterpret_cast<const float4*>(Wl + n * IN_P)[lane];

        float u0 = xa0.x * wl.x + xa0.y * wl.y + xa0.z * wl.z + xa0.w * wl.w;
        float u1 = xa1.x * wl.x + xa1.y * wl.y + xa1.z * wl.z + xa1.w * wl.w;
        float u2 = xa2.x * wl.x + xa2.y * wl.y + xa2.z * wl.z + xa2.w * wl.w;
        float u3 = xa3.x * wl.x + xa3.y * wl.y + xa3.z * wl.z + xa3.w * wl.w;

        #pragma unroll
        for (int mask = 1; mask < 64; mask <<= 1) {
            u0 += __shfl_xor(u0, mask, 64);
            u1 += __shfl_xor(u1, mask, 64);
            u2 += __shfl_xor(u2, mask, 64);
            u3 += __shfl_xor(u3, mask, 64);
        }

        const int q = n & 7;
        const float* rq = rule + q * 16;
        #pragma unroll
        for (int j = 0; j < 4; ++j)
            v[p][j] = rq[0 * 4 + j] * u0 + rq[1 * 4 + j] * u1
                    + rq[2 * 4 + j] * u2 + rq[3 * 4 + j] * u3;
    }

    // ---- phase 2: write 1024 floats (4 x 1KB coalesced wave-stores) ----
    float* orow = out + (size_t)s * OUT_COLS + m * OUT_F;
    #pragma unroll
    for (int j = 0; j < 4; ++j) {
        float4 acc = bv[j];
        #pragma unroll
        for (int p = 0; p < 4; ++p) {
            acc.x += v[p][j] * wr[p].x;
            acc.y += v[p][j] * wr[p].y;
            acc.z += v[p][j] * wr[p].z;
            acc.w += v[p][j] * wr[p].w;
        }
        reinterpret_cast<float4*>(orow + j * OUT_P)[lane] = acc;
    }
}

extern "C" void kernel_launch(void* const* d_in, const int* in_sizes, int n_in,
                              void* d_out, int out_size, void* d_ws, size_t ws_size,
                              hipStream_t stream) {
    const float* x    = (const float*)d_in[0];
    const float* Wl   = (const float*)d_in[1];
    const float* Wr   = (const float*)d_in[2];
    const float* rule = (const float*)d_in[3];
    const float* b    = (const float*)d_in[4];
    float* out = (float*)d_out;

    dim3 grid(BATCH * M2L);   // 3072 single-wave blocks
    dim3 block(64);
    phm_fused_kernel<<<grid, block, 0, stream>>>(x, Wl, Wr, rule, b, out);
}